// Round 1
// baseline (3724.784 us; speedup 1.0000x reference)
//
#include <hip/hip_runtime.h>

#define Bn 128
#define Wn 64
#define En 256
#define Dn 256
#define Fn 4

// enc_proj[b][w][e] = attn_b1[e] + sum_k W1e[e][k] * enc[b][w][k]   (8 MB, static device)
__device__ float g_eproj[Bn * Wn * En];

__device__ __forceinline__ float ftanh(float x) {
  // tanh(x) = 1 - 2/(exp2(2x*log2e)+1); v_exp_f32 + v_rcp_f32, handles +-inf gracefully
  float p = __builtin_exp2f(x * 2.885390081777927f);
  return 1.0f - 2.0f * __builtin_amdgcn_rcpf(p + 1.0f);
}
__device__ __forceinline__ float fsigm(float x) {
  float p = __builtin_exp2f(-x * 1.4426950408889634f);
  return __builtin_amdgcn_rcpf(1.0f + p);
}
__device__ __forceinline__ float wsum(float v) {
#pragma unroll
  for (int m = 32; m; m >>= 1) v += __shfl_xor(v, m, 64);
  return v;
}
__device__ __forceinline__ float dot4(float4 a, float4 b) {
  return a.x * b.x + a.y * b.y + a.z * b.z + a.w * b.w;  // contracts to v_fma
}

// ---------------- precompute enc_proj: GEMM M=8192(b,w) x N=256(e), K=256 ----------------
__global__ __launch_bounds__(256) void eproj_kernel(const float* __restrict__ enc,
                                                    const float* __restrict__ w1,
                                                    const float* __restrict__ b1) {
  __shared__ __align__(16) float4 encs[16][64];  // 16 M-rows x 256 floats
  const int m0 = blockIdx.x * 16;
  const int tid = threadIdx.x;
  const float4* eg = (const float4*)(enc + (size_t)m0 * En);
#pragma unroll
  for (int i = 0; i < 4; i++) {
    int idx = tid + 256 * i;
    encs[idx >> 6][idx & 63] = eg[idx];
  }
  __syncthreads();
  const int e = tid;
  float acc[16];
#pragma unroll
  for (int i = 0; i < 16; i++) acc[i] = 0.f;
  const float4* wrow = (const float4*)(w1 + e * 768 + 512);  // W1e row e
  for (int k4 = 0; k4 < 64; k4++) {
    float4 wv = wrow[k4];
#pragma unroll
    for (int i = 0; i < 16; i++) acc[i] += dot4(wv, encs[i][k4]);
  }
  float bb = b1[e];
#pragma unroll
  for (int i = 0; i < 16; i++) g_eproj[(size_t)(m0 + i) * En + e] = acc[i] + bb;
}

// ---------------- main decoder: one WG (256 thr) per batch element ----------------
__global__ __launch_bounds__(256) void decoder_kernel(
    const float* __restrict__ enc, const float* __restrict__ yhist,
    const float* __restrict__ w1, const float* __restrict__ w2,
    const float* __restrict__ w_ih, const float* __restrict__ w_hh,
    const float* __restrict__ b_ih, const float* __restrict__ b_hh,
    const float* __restrict__ fc_w, const float* __restrict__ fc_b,
    const float* __restrict__ fcf_w, const float* __restrict__ fcf_b,
    float* __restrict__ out) {
  __shared__ __align__(16) float hc[512];   // [h(256) | c(256)]
  __shared__ float hcp[En];                 // hc_proj
  __shared__ float ctx[En];                 // context
  __shared__ float att[Wn];                 // scores -> attn
  __shared__ __align__(16) float yh[Wn * Fn];
  __shared__ __align__(16) float ytil[4];

  const int b = blockIdx.x, tid = threadIdx.x;
  const int l = tid & 63, wv = tid >> 6;

  hc[tid] = 0.f;
  hc[tid + 256] = 0.f;
  if (tid < 64) ((float4*)yh)[tid] = ((const float4*)(yhist + (size_t)b * Wn * Fn))[tid];

  // per-lane resident small weights
  float w2v[4], fcw[4], fct[4];
#pragma unroll
  for (int j = 0; j < 4; j++) w2v[j] = w2[l + 64 * j];
#pragma unroll
  for (int j = 0; j < 4; j++) fcw[j] = fc_w[wv * 260 + l + 64 * j];
#pragma unroll
  for (int j = 0; j < 4; j++) fct[j] = fc_w[wv * 260 + 256 + j];
  const float fcb = fc_b[wv];
  float4 wih4[4];
  float bsum[4];
#pragma unroll
  for (int r = 0; r < 4; r++) {
    int jr = r * 256 + tid;  // thread owns gates (i,f,g,o) for d = tid
    wih4[r] = *(const float4*)(w_ih + jr * 4);
    bsum[r] = b_ih[jr] + b_hh[jr];
  }

  const float4* w1row = (const float4*)(w1 + (size_t)tid * 768);  // cols 0..511 = [W1h|W1c]
  const float* encb = enc + (size_t)b * Wn * En;
  const float* eproj_b = g_eproj + (size_t)b * Wn * En;
  const float4* hc4 = (const float4*)hc;
  const float4* wr0 = (const float4*)(w_hh + (size_t)(0 * 256 + tid) * 256);
  const float4* wr1 = (const float4*)(w_hh + (size_t)(1 * 256 + tid) * 256);
  const float4* wr2 = (const float4*)(w_hh + (size_t)(2 * 256 + tid) * 256);
  const float4* wr3 = (const float4*)(w_hh + (size_t)(3 * 256 + tid) * 256);

  __syncthreads();

  for (int t = 0; t < Wn; t++) {
    // ---- 1: hc_proj[e] = W1h[e,:].h + W1c[e,:].c  (streams 512 KB) ----
    {
      float a = 0.f;
#pragma unroll 8
      for (int k4 = 0; k4 < 128; k4++) a += dot4(w1row[k4], hc4[k4]);
      hcp[tid] = a;
    }
    __syncthreads();
    // ---- 2: scores[w] = sum_e w2[e]*tanh(eproj[w,e] + hcp[e]) ----
    {
      float hp[4];
#pragma unroll
      for (int j = 0; j < 4; j++) hp[j] = hcp[l + 64 * j];
      for (int wi = 0; wi < 16; wi++) {
        int w = wv * 16 + wi;
        float s = 0.f;
#pragma unroll
        for (int j = 0; j < 4; j++) {
          float x = eproj_b[(size_t)w * En + l + 64 * j] + hp[j];
          s += w2v[j] * ftanh(x);
        }
        s = wsum(s);
        if (l == 0) att[w] = s;
      }
    }
    __syncthreads();
    // ---- 3: softmax over W=64 (wave 0) ----
    if (tid < 64) {
      float s = att[tid];
      float m = s;
#pragma unroll
      for (int d = 32; d; d >>= 1) m = fmaxf(m, __shfl_xor(m, d, 64));
      float p = __builtin_exp2f((s - m) * 1.4426950408889634f);
      float su = p;
#pragma unroll
      for (int d = 32; d; d >>= 1) su += __shfl_xor(su, d, 64);
      att[tid] = p * __builtin_amdgcn_rcpf(su);
    }
    __syncthreads();
    // ---- 4: context[e] = sum_w attn[w]*enc[w,e] ----
    {
      float cacc = 0.f;
#pragma unroll 8
      for (int w = 0; w < Wn; w++) cacc += att[w] * encb[(size_t)w * En + tid];
      ctx[tid] = cacc;
    }
    __syncthreads();
    // ---- 5: y_tilde[f] = fc_w[f,:].[ctx|y_t] + fc_b[f]  (wave f) ----
    {
      float part = 0.f;
#pragma unroll
      for (int j = 0; j < 4; j++) part += fcw[j] * ctx[l + 64 * j];
      part = wsum(part);
      if (l == 0) {
        float v = part + fcb;
#pragma unroll
        for (int ff = 0; ff < 4; ff++) v += fct[ff] * yh[t * 4 + ff];
        ytil[wv] = v;
      }
    }
    __syncthreads();
    // ---- 6: gates (streams w_hh 1 MB) + LSTM elementwise ----
    {
      float4 yt4 = *(const float4*)ytil;
      float a0 = bsum[0] + dot4(wih4[0], yt4);
      float a1 = bsum[1] + dot4(wih4[1], yt4);
      float a2 = bsum[2] + dot4(wih4[2], yt4);
      float a3 = bsum[3] + dot4(wih4[3], yt4);
#pragma unroll 8
      for (int k4 = 0; k4 < 64; k4++) {
        float4 hv = hc4[k4];
        a0 += dot4(wr0[k4], hv);
        a1 += dot4(wr1[k4], hv);
        a2 += dot4(wr2[k4], hv);
        a3 += dot4(wr3[k4], hv);
      }
      float ig = fsigm(a0), fg = fsigm(a1);
      float gg = ftanh(a2), og = fsigm(a3);
      float cn = fg * hc[256 + tid] + ig * gg;
      float hn = og * ftanh(cn);
      __syncthreads();  // everyone done reading h,c
      hc[tid] = hn;
      hc[256 + tid] = cn;
    }
    __syncthreads();
  }

  // ---- final: out[b,f] = fcf_w[f,:].[h|ctx] + fcf_b[f]  (wave f) ----
  {
    float part = 0.f;
#pragma unroll
    for (int j = 0; j < 4; j++) {
      part += fcf_w[wv * 512 + l + 64 * j] * hc[l + 64 * j];
      part += fcf_w[wv * 512 + 256 + l + 64 * j] * ctx[l + 64 * j];
    }
    part = wsum(part);
    if (l == 0) out[b * Fn + wv] = part + fcf_b[wv];
  }
}

extern "C" void kernel_launch(void* const* d_in, const int* in_sizes, int n_in,
                              void* d_out, int out_size, void* d_ws, size_t ws_size,
                              hipStream_t stream) {
  (void)in_sizes; (void)n_in; (void)d_ws; (void)ws_size; (void)out_size;
  const float* enc   = (const float*)d_in[0];
  const float* yhist = (const float*)d_in[1];
  const float* w1    = (const float*)d_in[2];
  const float* b1    = (const float*)d_in[3];
  const float* w2    = (const float*)d_in[4];
  // d_in[5] = attn_b2: constant shift on scores, softmax-invariant -> unused
  const float* w_ih  = (const float*)d_in[6];
  const float* w_hh  = (const float*)d_in[7];
  const float* b_ih  = (const float*)d_in[8];
  const float* b_hh  = (const float*)d_in[9];
  const float* fc_w  = (const float*)d_in[10];
  const float* fc_b  = (const float*)d_in[11];
  const float* fcf_w = (const float*)d_in[12];
  const float* fcf_b = (const float*)d_in[13];
  float* out = (float*)d_out;

  eproj_kernel<<<dim3(512), dim3(256), 0, stream>>>(enc, w1, b1);
  decoder_kernel<<<dim3(Bn), dim3(256), 0, stream>>>(enc, yhist, w1, w2, w_ih, w_hh,
                                                     b_ih, b_hh, fc_w, fc_b, fcf_w,
                                                     fcf_b, out);
}

// Round 2
// 1520.083 us; speedup vs baseline: 2.4504x; 2.4504x over previous
//
#include <hip/hip_runtime.h>

#define Bn 128
#define Wn 64
#define En 256
#define Dn 256
#define Fn 4

typedef _Float16 h2 __attribute__((ext_vector_type(2)));

// enc_proj[b][w][e] = attn_b1[e] + sum_k W1e[e][k] * enc[b][w][k]   (8 MB fp32)
__device__ float g_eproj[Bn * Wn * En];
// transposed packed-f16 weights: [K8][col], each float4 = 8 halves k=8K8..8K8+7
__device__ float4 g_w1T[64 * 256];    // w1 cols 0..511 ([W1h|W1c]), col=e
__device__ float4 g_whhT[32 * 1024];  // w_hh, col=r (gate row)

__device__ __forceinline__ float ftanh(float x) {
  float p = __builtin_exp2f(x * 2.885390081777927f);
  return 1.0f - 2.0f * __builtin_amdgcn_rcpf(p + 1.0f);
}
__device__ __forceinline__ float fsigm(float x) {
  float p = __builtin_exp2f(-x * 1.4426950408889634f);
  return __builtin_amdgcn_rcpf(1.0f + p);
}
__device__ __forceinline__ float wsum(float v) {
#pragma unroll
  for (int m = 32; m; m >>= 1) v += __shfl_xor(v, m, 64);
  return v;
}
__device__ __forceinline__ float dot4(float4 a, float4 b) {
  return a.x * b.x + a.y * b.y + a.z * b.z + a.w * b.w;
}
__device__ __forceinline__ float fd2(unsigned w, unsigned h, float acc) {
  h2 a = __builtin_bit_cast(h2, w), b = __builtin_bit_cast(h2, h);
#if __has_builtin(__builtin_amdgcn_fdot2)
  return __builtin_amdgcn_fdot2(a, b, acc, false);
#else
  return acc + (float)a.x * (float)b.x + (float)a.y * (float)b.y;
#endif
}
__device__ __forceinline__ float fd2x4(float4 wv, uint4 hv, float acc) {
  acc = fd2(__builtin_bit_cast(unsigned, wv.x), hv.x, acc);
  acc = fd2(__builtin_bit_cast(unsigned, wv.y), hv.y, acc);
  acc = fd2(__builtin_bit_cast(unsigned, wv.z), hv.z, acc);
  acc = fd2(__builtin_bit_cast(unsigned, wv.w), hv.w, acc);
  return acc;
}
__device__ __forceinline__ unsigned pk(float a, float b) {
  h2 h = {(_Float16)a, (_Float16)b};
  return __builtin_bit_cast(unsigned, h);
}

// ---------------- eproj: GEMM M=8192(b,w) x N=256(e), K=256 ----------------
__global__ __launch_bounds__(256) void eproj_kernel(const float* __restrict__ enc,
                                                    const float* __restrict__ w1,
                                                    const float* __restrict__ b1) {
  __shared__ __align__(16) float4 encs[16][64];
  const int m0 = blockIdx.x * 16;
  const int tid = threadIdx.x;
  const float4* eg = (const float4*)(enc + (size_t)m0 * En);
#pragma unroll
  for (int i = 0; i < 4; i++) {
    int idx = tid + 256 * i;
    encs[idx >> 6][idx & 63] = eg[idx];
  }
  __syncthreads();
  const int e = tid;
  float acc[16];
#pragma unroll
  for (int i = 0; i < 16; i++) acc[i] = 0.f;
  const float4* wrow = (const float4*)(w1 + e * 768 + 512);
  for (int k4 = 0; k4 < 64; k4++) {
    float4 wv = wrow[k4];
#pragma unroll
    for (int i = 0; i < 16; i++) acc[i] += dot4(wv, encs[i][k4]);
  }
  float bb = b1[e];
#pragma unroll
  for (int i = 0; i < 16; i++) g_eproj[(size_t)(m0 + i) * En + e] = acc[i] + bb;
}

// ---------------- pack weights to transposed f16 ----------------
__global__ __launch_bounds__(256) void pack_kernel(const float* __restrict__ w1,
                                                   const float* __restrict__ w_hh) {
  int idx = blockIdx.x * 256 + threadIdx.x;
  const float* src;
  float4* dst;
  if (idx < 64 * 256) {
    int K8 = idx >> 8, e = idx & 255;
    src = w1 + e * 768 + 8 * K8;   // cols 0..511 region
    dst = g_w1T + idx;             // [K8][e]
  } else {
    int j = idx - 64 * 256;
    if (j >= 32 * 1024) return;
    int K8 = j >> 10, r = j & 1023;
    src = w_hh + r * 256 + 8 * K8;
    dst = g_whhT + j;              // [K8][r]
  }
  float4 o;
  o.x = __builtin_bit_cast(float, pk(src[0], src[1]));
  o.y = __builtin_bit_cast(float, pk(src[2], src[3]));
  o.z = __builtin_bit_cast(float, pk(src[4], src[5]));
  o.w = __builtin_bit_cast(float, pk(src[6], src[7]));
  *dst = o;
}

// ---------------- main decoder: one WG (512 thr) per batch element ----------------
__global__ __launch_bounds__(512) void decoder_kernel(
    const float* __restrict__ enc, const float* __restrict__ yhist,
    const float* __restrict__ w2,
    const float* __restrict__ w_ih, const float* __restrict__ b_ih,
    const float* __restrict__ b_hh,
    const float* __restrict__ fc_w, const float* __restrict__ fc_b,
    const float* __restrict__ fcf_w, const float* __restrict__ fcf_b,
    float* __restrict__ out) {
  __shared__ __align__(16) unsigned hc2[256];  // packed f16 pairs [h(128)|c(128)]
  __shared__ float hcp_p[2][256];
  __shared__ float ctx_p[2][256];
  __shared__ float h32[256], c32[256];
  __shared__ float ex0[256], ex1[256];
  __shared__ float att[Wn];
  __shared__ __align__(16) float yh[Wn * Fn];
  __shared__ __align__(16) float ytil[4];

  const int b = blockIdx.x, tid = threadIdx.x;
  const int l = tid & 63, wv = tid >> 6;   // wave 0..7
  const int e = tid & 255, kh = tid >> 8;  // K-half 0/1

  if (tid < 256) { hc2[tid] = 0u; h32[tid] = 0.f; }
  if (tid < 64) ((float4*)yh)[tid] = ((const float4*)(yhist + (size_t)b * Wn * Fn))[tid];

  const int wvm = wv & 3;
  float w2v[4], fcw[4], fct[4];
#pragma unroll
  for (int j = 0; j < 4; j++) w2v[j] = w2[l + 64 * j];
#pragma unroll
  for (int j = 0; j < 4; j++) fcw[j] = fc_w[wvm * 260 + l + 64 * j];
#pragma unroll
  for (int j = 0; j < 4; j++) fct[j] = fc_w[wvm * 260 + 256 + j];
  const float fcb = fc_b[wvm];

  // gate rows: tid<256 -> {i_d, g_d}, tid>=256 -> {f_d, o_d} (d = tid&255)
  const int r0 = tid, r1 = tid + 512;
  const float4 wih0 = *(const float4*)(w_ih + r0 * 4);
  const float4 wih1 = *(const float4*)(w_ih + r1 * 4);
  const float bs0 = b_ih[r0] + b_hh[r0];
  const float bs1 = b_ih[r1] + b_hh[r1];
  float creg = 0.f;

  const float* encb = enc + (size_t)b * Wn * En;
  const float* eproj_b = g_eproj + (size_t)b * Wn * En;
  const float4* w1p = g_w1T + kh * 32 * 256 + e;
  const float4* q0 = g_whhT + r0;
  const float4* q1 = g_whhT + r1;

  __syncthreads();

  for (int t = 0; t < Wn; t++) {
    // P1: hcp partial over K-half (coalesced f16 stream, 256 KB/WG)
    {
      float a = 0.f;
#pragma unroll 8
      for (int k8 = 0; k8 < 32; k8++) {
        float4 wv4 = w1p[k8 * 256];
        uint4 hv = *(const uint4*)&hc2[4 * (kh * 32 + k8)];
        a = fd2x4(wv4, hv, a);
      }
      hcp_p[kh][e] = a;
    }
    __syncthreads();
    // P2: scores, 8 waves x 8 w
    {
      float hp[4];
#pragma unroll
      for (int j = 0; j < 4; j++) hp[j] = hcp_p[0][l + 64 * j] + hcp_p[1][l + 64 * j];
#pragma unroll
      for (int wi = 0; wi < 8; wi++) {
        int w = wv * 8 + wi;
        float s = 0.f;
#pragma unroll
        for (int j = 0; j < 4; j++) {
          float x = eproj_b[(size_t)w * En + l + 64 * j] + hp[j];
          s += w2v[j] * ftanh(x);
        }
        s = wsum(s);
        if (l == 0) att[w] = s;
      }
    }
    __syncthreads();
    // P3: softmax over W=64 (wave 0)
    if (tid < 64) {
      float s = att[tid];
      float m = s;
#pragma unroll
      for (int d = 32; d; d >>= 1) m = fmaxf(m, __shfl_xor(m, d, 64));
      float p = __builtin_exp2f((s - m) * 1.4426950408889634f);
      float su = p;
#pragma unroll
      for (int d = 32; d; d >>= 1) su += __shfl_xor(su, d, 64);
      att[tid] = p * __builtin_amdgcn_rcpf(su);
    }
    __syncthreads();
    // P4: context partial over w-half
    {
      float ca = 0.f;
      const float* ep = encb + (size_t)(kh * 32) * En + e;
#pragma unroll 8
      for (int w = 0; w < 32; w++) ca += att[kh * 32 + w] * ep[(size_t)w * En];
      ctx_p[kh][e] = ca;
    }
    __syncthreads();
    // P5: y_tilde (waves 0..3)
    if (tid < 256) {
      float part = 0.f;
#pragma unroll
      for (int j = 0; j < 4; j++)
        part += fcw[j] * (ctx_p[0][l + 64 * j] + ctx_p[1][l + 64 * j]);
      part = wsum(part);
      if (l == 0) {
        float v = part + fcb;
#pragma unroll
        for (int ff = 0; ff < 4; ff++) v += fct[ff] * yh[t * 4 + ff];
        ytil[wv] = v;
      }
    }
    __syncthreads();
    // P6: gates, 2 rows/thread (coalesced f16 stream, 512 KB/WG)
    float a0, a1;
    {
      float4 yt4 = *(const float4*)ytil;
      a0 = bs0 + dot4(wih0, yt4);
      a1 = bs1 + dot4(wih1, yt4);
#pragma unroll 8
      for (int K8 = 0; K8 < 32; K8++) {
        uint4 hv = *(const uint4*)&hc2[4 * K8];  // h pairs
        float4 w0 = q0[K8 * 1024];
        float4 w1v = q1[K8 * 1024];
        a0 = fd2x4(w0, hv, a0);
        a1 = fd2x4(w1v, hv, a1);
      }
    }
    // P7: elementwise LSTM update
    if (tid >= 256) { ex0[tid - 256] = fsigm(a0); ex1[tid - 256] = fsigm(a1); }
    __syncthreads();
    if (tid < 256) {
      float cn = ex0[tid] * creg + fsigm(a0) * ftanh(a1);
      float hn = ex1[tid] * ftanh(cn);
      creg = cn;
      h32[tid] = hn;
      c32[tid] = cn;
    }
    __syncthreads();
    if (tid < 128) {
      hc2[tid] = pk(h32[2 * tid], h32[2 * tid + 1]);
      hc2[128 + tid] = pk(c32[2 * tid], c32[2 * tid + 1]);
    }
    __syncthreads();
  }

  // final: out[b,f] = fcf_w[f,:].[h|ctx] + fcf_b[f]
  if (tid < 256) {
    float part = 0.f;
#pragma unroll
    for (int j = 0; j < 4; j++) {
      int ee = l + 64 * j;
      part += fcf_w[wvm * 512 + ee] * h32[ee];
      part += fcf_w[wvm * 512 + 256 + ee] * (ctx_p[0][ee] + ctx_p[1][ee]);
    }
    part = wsum(part);
    if (l == 0) out[b * Fn + wv] = part + fcf_b[wv];
  }
}

extern "C" void kernel_launch(void* const* d_in, const int* in_sizes, int n_in,
                              void* d_out, int out_size, void* d_ws, size_t ws_size,
                              hipStream_t stream) {
  (void)in_sizes; (void)n_in; (void)d_ws; (void)ws_size; (void)out_size;
  const float* enc   = (const float*)d_in[0];
  const float* yhist = (const float*)d_in[1];
  const float* w1    = (const float*)d_in[2];
  const float* b1    = (const float*)d_in[3];
  const float* w2    = (const float*)d_in[4];
  // d_in[5] = attn_b2: softmax-invariant -> unused
  const float* w_ih  = (const float*)d_in[6];
  const float* w_hh  = (const float*)d_in[7];
  const float* b_ih  = (const float*)d_in[8];
  const float* b_hh  = (const float*)d_in[9];
  const float* fc_w  = (const float*)d_in[10];
  const float* fc_b  = (const float*)d_in[11];
  const float* fcf_w = (const float*)d_in[12];
  const float* fcf_b = (const float*)d_in[13];
  float* out = (float*)d_out;

  pack_kernel<<<dim3(192), dim3(256), 0, stream>>>(w1, w_hh);
  eproj_kernel<<<dim3(512), dim3(256), 0, stream>>>(enc, w1, b1);
  decoder_kernel<<<dim3(Bn), dim3(512), 0, stream>>>(enc, yhist, w2, w_ih, b_ih, b_hh,
                                                     fc_w, fc_b, fcf_w, fcf_b, out);
}

// Round 3
// 762.705 us; speedup vs baseline: 4.8836x; 1.9930x over previous
//
#include <hip/hip_runtime.h>

#define Bn 128
#define Wn 64
#define En 256
#define Dn 256
#define Fn 4

typedef _Float16 h2 __attribute__((ext_vector_type(2)));

// ---- inter-WG exchange state (static device; flags reset every launch) ----
__device__ unsigned g_f1[256];          // hcp-half ready, value = t+1
__device__ unsigned g_f2[256];          // state-half ready, value = t+1
__device__ unsigned g_hcx[256][128];    // hcp half (f32 bits), per WG
__device__ unsigned g_state[256][128];  // [0..64) h-pairs f16, [64..128) c-pairs
__device__ unsigned g_ep16[Bn * Wn * 128];   // eproj f16 pairs [b][w][128]
__device__ unsigned g_enc16[Bn * Wn * 128];  // enc   f16 pairs [b][w][128]

__device__ __forceinline__ float ftanh(float x) {
  float p = __builtin_exp2f(x * 2.885390081777927f);
  return 1.0f - 2.0f * __builtin_amdgcn_rcpf(p + 1.0f);
}
__device__ __forceinline__ float fsigm(float x) {
  float p = __builtin_exp2f(-x * 1.4426950408889634f);
  return __builtin_amdgcn_rcpf(1.0f + p);
}
__device__ __forceinline__ float dot4(float4 a, float4 b) {
  return a.x * b.x + a.y * b.y + a.z * b.z + a.w * b.w;
}
__device__ __forceinline__ float fd2(unsigned w, unsigned h, float acc) {
  h2 a = __builtin_bit_cast(h2, w), b = __builtin_bit_cast(h2, h);
#if __has_builtin(__builtin_amdgcn_fdot2)
  return __builtin_amdgcn_fdot2(a, b, acc, false);
#else
  return acc + (float)a.x * (float)b.x + (float)a.y * (float)b.y;
#endif
}
__device__ __forceinline__ float fd2x4u(uint4 w, uint4 h, float acc) {
  acc = fd2(w.x, h.x, acc);
  acc = fd2(w.y, h.y, acc);
  acc = fd2(w.z, h.z, acc);
  acc = fd2(w.w, h.w, acc);
  return acc;
}
__device__ __forceinline__ unsigned pk(float a, float b) {
  h2 h = {(_Float16)a, (_Float16)b};
  return __builtin_bit_cast(unsigned, h);
}
__device__ __forceinline__ void ast(unsigned* p, unsigned v) {
  __hip_atomic_store(p, v, __ATOMIC_RELAXED, __HIP_MEMORY_SCOPE_AGENT);
}
__device__ __forceinline__ unsigned ald(unsigned* p) {
  return __hip_atomic_load(p, __ATOMIC_RELAXED, __HIP_MEMORY_SCOPE_AGENT);
}

// ---------------- flag reset (runs every launch, stream-ordered) ----------------
__global__ void reset_flags() {
  int t = threadIdx.x;
  if (t < 256) { g_f1[t] = 0u; g_f2[t] = 0u; }
}

// ---------------- enc -> f16 pairs ----------------
__global__ __launch_bounds__(256) void pack_enc(const float* __restrict__ enc) {
  int idx = blockIdx.x * 256 + threadIdx.x;  // < 1048576
  g_enc16[idx] = pk(enc[2 * idx], enc[2 * idx + 1]);
}

// ---------------- eproj: GEMM M=8192(b,w) x N=256(e), K=256 -> f16 pairs ----------------
__global__ __launch_bounds__(256) void eproj_kernel(const float* __restrict__ enc,
                                                    const float* __restrict__ w1,
                                                    const float* __restrict__ b1) {
  __shared__ __align__(16) float4 encs[16][64];
  __shared__ float accs[16][256];
  const int m0 = blockIdx.x * 16;
  const int tid = threadIdx.x;
  const float4* eg = (const float4*)(enc + (size_t)m0 * En);
#pragma unroll
  for (int i = 0; i < 4; i++) {
    int idx = tid + 256 * i;
    encs[idx >> 6][idx & 63] = eg[idx];
  }
  __syncthreads();
  const int e = tid;
  float acc[16];
#pragma unroll
  for (int i = 0; i < 16; i++) acc[i] = 0.f;
  const float4* wrow = (const float4*)(w1 + e * 768 + 512);
  for (int k4 = 0; k4 < 64; k4++) {
    float4 wv = wrow[k4];
#pragma unroll
    for (int i = 0; i < 16; i++) acc[i] += dot4(wv, encs[i][k4]);
  }
  float bb = b1[e];
#pragma unroll
  for (int i = 0; i < 16; i++) accs[i][e] = acc[i] + bb;
  __syncthreads();
#pragma unroll
  for (int r = 0; r < 8; r++) {
    int idx = r * 256 + tid;  // 0..2047
    int i = idx >> 7, jp = idx & 127;
    g_ep16[(size_t)(m0 + i) * 128 + jp] = pk(accs[i][2 * jp], accs[i][2 * jp + 1]);
  }
}

// ---------------- decoder: WG pair per batch chain; weights register-resident ----------------
__global__ __launch_bounds__(512, 2) void decoder_kernel(
    const float* __restrict__ w1, const float* __restrict__ w_hh,
    const float* __restrict__ yhist, const float* __restrict__ w2,
    const float* __restrict__ w_ih, const float* __restrict__ b_ih,
    const float* __restrict__ b_hh,
    const float* __restrict__ fc_w, const float* __restrict__ fc_b,
    const float* __restrict__ fcf_w, const float* __restrict__ fcf_b,
    float* __restrict__ out) {
  __shared__ unsigned ep16[64 * 132];   // eproj pairs, padded stride (bank-friendly)
  __shared__ unsigned en16[128 * 65];   // enc pairs transposed [ep][w], stride 65
  __shared__ float hcp_l[256];
  __shared__ unsigned st_l[256];        // h pairs [0..128), c pairs [128..256)
  __shared__ float ctx_l[256];
  __shared__ float w2_l[256];
  __shared__ float att_l[64];
  __shared__ __align__(16) float yh_l[256];
  __shared__ __align__(16) float ytil[4];
  __shared__ float g4_l[4][128];
  __shared__ float hn_l[128];
  __shared__ float c32_l[128];

  const int g = blockIdx.x, tid = threadIdx.x;
  const int b = g & 127, p = g >> 7, other = g ^ 128;
  const int l = tid & 63, wv = tid >> 6;

  // ---- register-resident weight halves (static-indexed, fully unrolled) ----
  const int e_own = 128 * p + (tid >> 2), kq = tid & 3;
  uint4 w1r[16];  // 128 f16 of w1[e_own][128*kq .. +128) over [h|c]
  {
    const float4* s = (const float4*)(w1 + (size_t)e_own * 768 + kq * 128);
#pragma unroll
    for (int i = 0; i < 16; i++) {
      float4 a = s[2 * i], c = s[2 * i + 1];
      w1r[i].x = pk(a.x, a.y); w1r[i].y = pk(a.z, a.w);
      w1r[i].z = pk(c.x, c.y); w1r[i].w = pk(c.z, c.w);
    }
  }
  const int q = tid >> 7, d_own = 128 * p + (tid & 127);
  const int row = q * 256 + d_own;  // gate row (i,f,g,o blocks)
  uint4 wr[32];                     // full 256-f16 w_hh row
  {
    const float4* s = (const float4*)(w_hh + (size_t)row * 256);
#pragma unroll
    for (int i = 0; i < 32; i++) {
      float4 a = s[2 * i], c = s[2 * i + 1];
      wr[i].x = pk(a.x, a.y); wr[i].y = pk(a.z, a.w);
      wr[i].z = pk(c.x, c.y); wr[i].w = pk(c.z, c.w);
    }
  }
  const float4 wih = *(const float4*)(w_ih + (size_t)row * 4);
  const float bsum = b_ih[row] + b_hh[row];
  const int wvm = wv & 3;
  float fcw[4], fct[4];
#pragma unroll
  for (int j = 0; j < 4; j++) fcw[j] = fc_w[wvm * 260 + l + 64 * j];
#pragma unroll
  for (int j = 0; j < 4; j++) fct[j] = fc_w[wvm * 260 + 256 + j];
  const float fcb = fc_b[wvm];

  // ---- LDS init ----
  if (tid < 256) { st_l[tid] = 0u; w2_l[tid] = w2[tid]; }
  if (tid < 128) c32_l[tid] = 0.f;
  if (tid < 64) ((float4*)yh_l)[tid] = ((const float4*)(yhist + (size_t)b * 256))[tid];
  {
    const int w = tid >> 3, j = tid & 7;
    const uint4* s = (const uint4*)(g_ep16 + ((size_t)b * 64 + w) * 128 + j * 16);
    unsigned* dst = &ep16[w * 132 + j * 16];
#pragma unroll
    for (int i = 0; i < 4; i++) *(uint4*)(dst + 4 * i) = s[i];
    const uint4* s2 = (const uint4*)(g_enc16 + ((size_t)b * 64 + w) * 128 + j * 16);
#pragma unroll
    for (int i = 0; i < 4; i++) {
      uint4 v = s2[i];
      int ep0 = j * 16 + 4 * i;
      en16[(ep0 + 0) * 65 + w] = v.x;
      en16[(ep0 + 1) * 65 + w] = v.y;
      en16[(ep0 + 2) * 65 + w] = v.z;
      en16[(ep0 + 3) * 65 + w] = v.w;
    }
  }
  __syncthreads();

  for (int t = 0; t < Wn; t++) {
    const unsigned want = (unsigned)(t + 1);
    // ---- P1: hcp[e_own] over full K=512 (4 threads/e, k-quarters) ----
    {
      float a = 0.f;
      const uint4* hv = (const uint4*)&st_l[kq * 64];
#pragma unroll
      for (int i = 0; i < 16; i++) a = fd2x4u(w1r[i], hv[i], a);
      a += __shfl_xor(a, 1, 64);
      a += __shfl_xor(a, 2, 64);
      if (kq == 0) {
        hcp_l[e_own] = a;
        ast(&g_hcx[g][tid >> 2], __builtin_bit_cast(unsigned, a));
      }
    }
    __syncthreads();  // drains vmem -> hcx globally visible
    if (tid == 0) {
      ast(&g_f1[g], want);
      while (ald(&g_f1[other]) < want) __builtin_amdgcn_s_sleep(1);
    }
    __syncthreads();
    if (tid < 128)
      hcp_l[128 * (1 - p) + tid] = __builtin_bit_cast(float, ald(&g_hcx[other][tid]));
    __syncthreads();
    // ---- P2: scores (redundant in both WGs) ----
    {
      const int w = tid >> 3, j = tid & 7;
      const unsigned* epw = &ep16[w * 132 + j * 16];
      float s = 0.f;
#pragma unroll
      for (int i = 0; i < 4; i++) {
        uint4 u = *(const uint4*)(epw + 4 * i);
        int e0 = 32 * j + 8 * i;
        float4 h0 = *(const float4*)&hcp_l[e0];
        float4 h1 = *(const float4*)&hcp_l[e0 + 4];
        float4 v0 = *(const float4*)&w2_l[e0];
        float4 v1 = *(const float4*)&w2_l[e0 + 4];
        h2 a;
        a = __builtin_bit_cast(h2, u.x);
        s += v0.x * ftanh((float)a.x + h0.x) + v0.y * ftanh((float)a.y + h0.y);
        a = __builtin_bit_cast(h2, u.y);
        s += v0.z * ftanh((float)a.x + h0.z) + v0.w * ftanh((float)a.y + h0.w);
        a = __builtin_bit_cast(h2, u.z);
        s += v1.x * ftanh((float)a.x + h1.x) + v1.y * ftanh((float)a.y + h1.y);
        a = __builtin_bit_cast(h2, u.w);
        s += v1.z * ftanh((float)a.x + h1.z) + v1.w * ftanh((float)a.y + h1.w);
      }
      s += __shfl_xor(s, 1, 64);
      s += __shfl_xor(s, 2, 64);
      s += __shfl_xor(s, 4, 64);
      if (j == 0) att_l[w] = s;
    }
    __syncthreads();
    // ---- P3: softmax over W=64 (wave 0) ----
    if (tid < 64) {
      float s = att_l[tid], m = s;
#pragma unroll
      for (int dd = 32; dd; dd >>= 1) m = fmaxf(m, __shfl_xor(m, dd, 64));
      float pr = __builtin_exp2f((s - m) * 1.4426950408889634f);
      float su = pr;
#pragma unroll
      for (int dd = 32; dd; dd >>= 1) su += __shfl_xor(su, dd, 64);
      att_l[tid] = pr * __builtin_amdgcn_rcpf(su);
    }
    __syncthreads();
    // ---- P4: context (4 threads per e-pair, w-quarters) ----
    {
      const int ep = tid >> 2, wq = tid & 3;
      const unsigned* ev = &en16[ep * 65 + wq * 16];
      float cx = 0.f, cy = 0.f;
#pragma unroll
      for (int i = 0; i < 16; i++) {
        float aw = att_l[wq * 16 + i];
        h2 pe = __builtin_bit_cast(h2, ev[i]);
        cx += aw * (float)pe.x;
        cy += aw * (float)pe.y;
      }
      cx += __shfl_xor(cx, 1, 64); cx += __shfl_xor(cx, 2, 64);
      cy += __shfl_xor(cy, 1, 64); cy += __shfl_xor(cy, 2, 64);
      if (wq == 0) { ctx_l[2 * ep] = cx; ctx_l[2 * ep + 1] = cy; }
    }
    __syncthreads();
    // ---- P5: y_tilde (waves 0..3) ----
    if (tid < 256) {
      float part = 0.f;
#pragma unroll
      for (int j2 = 0; j2 < 4; j2++) part += fcw[j2] * ctx_l[l + 64 * j2];
#pragma unroll
      for (int m2 = 32; m2; m2 >>= 1) part += __shfl_xor(part, m2, 64);
      if (l == 0) {
        float v = part + fcb;
#pragma unroll
        for (int ff = 0; ff < 4; ff++) v += fct[ff] * yh_l[t * 4 + ff];
        ytil[wvm] = v;
      }
    }
    __syncthreads();
    // ---- P6: gates from register-resident w_hh (one row/thread) ----
    {
      float4 y4 = *(const float4*)ytil;
      float a = bsum + dot4(wih, y4);
      const uint4* hv = (const uint4*)st_l;  // h pairs, broadcast
#pragma unroll
      for (int i = 0; i < 32; i++) a = fd2x4u(wr[i], hv[i], a);
      g4_l[q][tid & 127] = a;
    }
    __syncthreads();
    // ---- P7: LSTM elementwise (own d-half) ----
    if (tid < 128) {
      float ig = fsigm(g4_l[0][tid]), fg = fsigm(g4_l[1][tid]);
      float gg = ftanh(g4_l[2][tid]), og = fsigm(g4_l[3][tid]);
      float cn = fg * c32_l[tid] + ig * gg;
      float hn = og * ftanh(cn);
      c32_l[tid] = cn;
      hn_l[tid] = hn;
    }
    __syncthreads();
    if (tid < 64) {
      unsigned hp = pk(hn_l[2 * tid], hn_l[2 * tid + 1]);
      unsigned cp = pk(c32_l[2 * tid], c32_l[2 * tid + 1]);
      st_l[64 * p + tid] = hp;
      st_l[128 + 64 * p + tid] = cp;
      ast(&g_state[g][tid], hp);
      ast(&g_state[g][64 + tid], cp);
    }
    __syncthreads();  // drains vmem -> state globally visible
    if (tid == 0) {
      ast(&g_f2[g], want);
      while (ald(&g_f2[other]) < want) __builtin_amdgcn_s_sleep(1);
    }
    __syncthreads();
    if (tid < 128) {
      unsigned v = ald(&g_state[other][tid]);
      int po = 1 - p;
      if (tid < 64) st_l[64 * po + tid] = v;
      else st_l[128 + 64 * po + (tid - 64)] = v;
    }
    __syncthreads();
  }

  // ---- final: out[b,f] = fcf_w[f,:].[h|ctx] + fcf_b[f] (p==0 writes) ----
  if (p == 0 && tid < 256) {
    float part = 0.f;
#pragma unroll
    for (int j2 = 0; j2 < 4; j2++) {
      int ee = l + 64 * j2;
      h2 hh = __builtin_bit_cast(h2, st_l[ee >> 1]);
      float hval = (ee & 1) ? (float)hh.y : (float)hh.x;
      part += fcf_w[wvm * 512 + ee] * hval + fcf_w[wvm * 512 + 256 + ee] * ctx_l[ee];
    }
#pragma unroll
    for (int m2 = 32; m2; m2 >>= 1) part += __shfl_xor(part, m2, 64);
    if (l == 0) out[b * 4 + wvm] = part + fcf_b[wvm];
  }
}

extern "C" void kernel_launch(void* const* d_in, const int* in_sizes, int n_in,
                              void* d_out, int out_size, void* d_ws, size_t ws_size,
                              hipStream_t stream) {
  (void)in_sizes; (void)n_in; (void)d_ws; (void)ws_size; (void)out_size;
  const float* enc   = (const float*)d_in[0];
  const float* yhist = (const float*)d_in[1];
  const float* w1    = (const float*)d_in[2];
  const float* b1    = (const float*)d_in[3];
  const float* w2    = (const float*)d_in[4];
  // d_in[5] = attn_b2: softmax-invariant -> unused
  const float* w_ih  = (const float*)d_in[6];
  const float* w_hh  = (const float*)d_in[7];
  const float* b_ih  = (const float*)d_in[8];
  const float* b_hh  = (const float*)d_in[9];
  const float* fc_w  = (const float*)d_in[10];
  const float* fc_b  = (const float*)d_in[11];
  const float* fcf_w = (const float*)d_in[12];
  const float* fcf_b = (const float*)d_in[13];
  float* out = (float*)d_out;

  reset_flags<<<dim3(1), dim3(256), 0, stream>>>();
  pack_enc<<<dim3(4096), dim3(256), 0, stream>>>(enc);
  eproj_kernel<<<dim3(512), dim3(256), 0, stream>>>(enc, w1, b1);
  decoder_kernel<<<dim3(256), dim3(512), 0, stream>>>(w1, w_hh, yhist, w2, w_ih, b_ih,
                                                      b_hh, fc_w, fc_b, fcf_w, fcf_b, out);
}